// Round 2
// baseline (76.300 us; speedup 1.0000x reference)
//
#include <hip/hip_runtime.h>
#include <math.h>

#define POOL 7
#define NUM_ROIS 300
#define FH 50
#define FW 50
#define FC 512
#define NBINS (NUM_ROIS * POOL * POOL)        // 14700

// Kernel A: fmax[h][w] = max over C of feature_maps[h][w][c]
// One wave (64 lanes) per pixel; 512 floats = 128 float4, 2 per lane.
__global__ __launch_bounds__(64) void channel_max_kernel(
    const float* __restrict__ fm, float* __restrict__ fmax_g) {
    int pix = blockIdx.x;                       // 0..2499
    int lane = threadIdx.x;                     // 0..63
    const float4* p = (const float4*)(fm + (size_t)pix * FC);
    float4 a = p[lane];
    float4 b = p[lane + 64];
    float m = fmaxf(fmaxf(fmaxf(a.x, a.y), fmaxf(a.z, a.w)),
                    fmaxf(fmaxf(b.x, b.y), fmaxf(b.z, b.w)));
    #pragma unroll
    for (int off = 32; off > 0; off >>= 1)
        m = fmaxf(m, __shfl_down(m, off, 64));
    if (lane == 0) fmax_g[pix] = m;
}

// Kernel B: one wave per ROI; lanes 0..48 each compute one bin's max over the
// LDS-staged 50x50 fmax map. Writes pooled[300*49] scalars.
__global__ __launch_bounds__(64) void pool_bins_kernel(
    const float* __restrict__ rois, const float* __restrict__ fmax_g,
    float* __restrict__ pooled_g) {
    __shared__ float sfmax[FH * FW];            // 10 KB
    int n = blockIdx.x;
    int lane = threadIdx.x;

    // Stage the map: 625 float4 across 64 lanes (~10 iters).
    const float4* src4 = (const float4*)fmax_g;
    float4* dst4 = (float4*)sfmax;
    for (int t = lane; t < (FH * FW) / 4; t += 64) dst4[t] = src4[t];
    // 2500 % 4 == 0, so no tail.

    // Replicate: r = int32(roi * (1/16)) (truncation; values non-negative).
    int x1 = (int)(rois[n * 5 + 1] * 0.0625f);
    int y1 = (int)(rois[n * 5 + 2] * 0.0625f);
    int x2 = (int)(rois[n * 5 + 3] * 0.0625f);
    int y2 = (int)(rois[n * 5 + 4] * 0.0625f);
    int rh = y2 - y1 + 1;
    int rw = x2 - x1 + 1;

    __syncthreads();

    if (lane < POOL * POOL) {
        int i = lane / POOL;                    // row bin
        int j = lane % POOL;                    // col bin
        // Python floor-div on non-negative ints == C int division here.
        int hs = min(max(y1 + (i * rh) / POOL, 0), FH);
        int he = min(max(y1 + ((i + 1) * rh + POOL - 1) / POOL, 0), FH);
        int ws = min(max(x1 + (j * rw) / POOL, 0), FW);
        int we = min(max(x1 + ((j + 1) * rw + POOL - 1) / POOL, 0), FW);
        float m = -INFINITY;                    // empty bin -> -inf (matches ref)
        for (int h = hs; h < he; ++h)
            for (int w = ws; w < we; ++w)
                m = fmaxf(m, sfmax[h * FW + w]);
        pooled_g[n * (POOL * POOL) + lane] = m;
    }
}

// Kernel C: pure streaming broadcast: out[n][bin][c] = pooled[n][bin].
// Grid-stride over 1,881,600 float4 (30 MB), fully coalesced.
__global__ __launch_bounds__(256) void broadcast_kernel(
    const float* __restrict__ pooled_g, float* __restrict__ out) {
    const int total4 = NBINS * (FC / 4);        // 1,881,600
    int stride = gridDim.x * blockDim.x;
    for (int t = blockIdx.x * blockDim.x + threadIdx.x; t < total4; t += stride) {
        float v = pooled_g[t >> 7];             // t / (512/4); wave-uniform index
        ((float4*)out)[t] = make_float4(v, v, v, v);
    }
}

extern "C" void kernel_launch(void* const* d_in, const int* in_sizes, int n_in,
                              void* d_out, int out_size, void* d_ws, size_t ws_size,
                              hipStream_t stream) {
    const float* rois = (const float*)d_in[0];          // (300, 5) f32
    const float* feature_maps = (const float*)d_in[1];  // (50, 50, 512) f32
    float* out = (float*)d_out;                         // (300, 7, 7, 512) f32
    float* fmax_g = (float*)d_ws;                       // 2500 floats
    float* pooled_g = fmax_g + FH * FW;                 // 14700 floats

    channel_max_kernel<<<FH * FW, 64, 0, stream>>>(feature_maps, fmax_g);
    pool_bins_kernel<<<NUM_ROIS, 64, 0, stream>>>(rois, fmax_g, pooled_g);
    broadcast_kernel<<<2560, 256, 0, stream>>>(pooled_g, out);
}

// Round 3
// 73.697 us; speedup vs baseline: 1.0353x; 1.0353x over previous
//
#include <hip/hip_runtime.h>
#include <math.h>

#define POOL 7
#define NUM_ROIS 300
#define FH 50
#define FW 50
#define FC 512
#define NBINS (POOL * POOL)                    // 49 bins per ROI

// Kernel A: fmax[h][w] = max over C of feature_maps[h][w][c]
// One wave (64 lanes) per pixel; 512 floats = 128 float4, 2 per lane.
__global__ __launch_bounds__(64) void channel_max_kernel(
    const float* __restrict__ fm, float* __restrict__ fmax_g) {
    int pix = blockIdx.x;                       // 0..2499
    int lane = threadIdx.x;                     // 0..63
    const float4* p = (const float4*)(fm + (size_t)pix * FC);
    float4 a = p[lane];
    float4 b = p[lane + 64];
    float m = fmaxf(fmaxf(fmaxf(a.x, a.y), fmaxf(a.z, a.w)),
                    fmaxf(fmaxf(b.x, b.y), fmaxf(b.z, b.w)));
    #pragma unroll
    for (int off = 32; off > 0; off >>= 1)
        m = fmaxf(m, __shfl_down(m, off, 64));
    if (lane == 0) fmax_g[pix] = m;
}

// Kernel B (fused pool+broadcast): one wave per (roi, bin). All 64 lanes
// redundantly compute the bin max (same-address loads broadcast from L1/L2),
// then each lane writes 2 float4 of the 512-channel broadcast slice.
__global__ __launch_bounds__(64) void pool_broadcast_kernel(
    const float* __restrict__ rois, const float* __restrict__ fmax_g,
    float* __restrict__ out) {
    int b = blockIdx.x;                         // 0..14699
    int n = b / NBINS;                          // roi
    int k = b - n * NBINS;                      // bin 0..48
    int i = k / POOL;                           // row bin
    int j = k - i * POOL;                       // col bin
    int lane = threadIdx.x;

    // Replicate: r = int32(roi * (1/16)) (truncation; values non-negative).
    int x1 = (int)(rois[n * 5 + 1] * 0.0625f);
    int y1 = (int)(rois[n * 5 + 2] * 0.0625f);
    int x2 = (int)(rois[n * 5 + 3] * 0.0625f);
    int y2 = (int)(rois[n * 5 + 4] * 0.0625f);
    int rh = y2 - y1 + 1;
    int rw = x2 - x1 + 1;

    // Python floor-div on non-negative ints == C int division here.
    int hs = min(max(y1 + (i * rh) / POOL, 0), FH);
    int he = min(max(y1 + ((i + 1) * rh + POOL - 1) / POOL, 0), FH);
    int ws = min(max(x1 + (j * rw) / POOL, 0), FW);
    int we = min(max(x1 + ((j + 1) * rw + POOL - 1) / POOL, 0), FW);

    float m = -INFINITY;                        // empty bin -> -inf (matches ref)
    for (int h = hs; h < he; ++h)
        for (int w = ws; w < we; ++w)
            m = fmaxf(m, fmax_g[h * FW + w]);   // wave-uniform addr -> broadcast

    // Write 512 channels = 128 float4; 2 per lane, coalesced.
    float4* o4 = (float4*)(out + (size_t)b * FC);
    float4 v = make_float4(m, m, m, m);
    o4[lane] = v;
    o4[lane + 64] = v;
}

extern "C" void kernel_launch(void* const* d_in, const int* in_sizes, int n_in,
                              void* d_out, int out_size, void* d_ws, size_t ws_size,
                              hipStream_t stream) {
    const float* rois = (const float*)d_in[0];          // (300, 5) f32
    const float* feature_maps = (const float*)d_in[1];  // (50, 50, 512) f32
    float* out = (float*)d_out;                         // (300, 7, 7, 512) f32
    float* fmax_g = (float*)d_ws;                       // 2500 floats

    channel_max_kernel<<<FH * FW, 64, 0, stream>>>(feature_maps, fmax_g);
    pool_broadcast_kernel<<<NUM_ROIS * NBINS, 64, 0, stream>>>(rois, fmax_g, out);
}